// Round 1
// 262.980 us; speedup vs baseline: 1.1240x; 1.1240x over previous
//
#include <hip/hip_runtime.h>
#include <math.h>

#define NROWS 500000
#define NGRP  50000
#define NEG   0.2f
#define GPB   16          // groups per block (50000/16 = 3125 exactly)

typedef __attribute__((ext_vector_type(8))) short bf16x8;   // 8 bf16 = 4 VGPRs
typedef __attribute__((ext_vector_type(4))) float f32x4;    // MFMA C/D
typedef unsigned int uint32;

__device__ __forceinline__ float leaky(float h) { return h >= 0.f ? h : NEG * h; }
__device__ __forceinline__ unsigned short f2bf(float v) {   // RNE
    uint32 u = __float_as_uint(v);
    u += 0x7FFFu + ((u >> 16) & 1u);
    return (unsigned short)(u >> 16);
}
__device__ __forceinline__ float bf2f(unsigned short h) {
    return __uint_as_float((uint32)h << 16);
}

// ---------------------------------------------------------------------------
// K0: pack Wsum = W1a+W1b+W1c and W2 into bf16 MFMA B-fragment-major layout:
//   frag[((ks*64 + n)*4 + q)*8 + j] = W[ks*32 + q*8 + j][n]
// Also pack W1bc (w1 rows 64..191, the [mn;mx] weights, K=128) in the same
// layout as a bf16 hi/lo PAIR (hi = RNE(w), lo = RNE(w - hi)) so the bias
// GEMM can run on MFMA at ~fp32 accuracy (err ~2^-17 rel, dropping lo*lo).
__global__ void k0_frag(const float* __restrict__ w1, const float* __restrict__ w2,
                        unsigned short* __restrict__ wsf, unsigned short* __restrict__ w2f,
                        unsigned short* __restrict__ wbh, unsigned short* __restrict__ wbl) {
    int r = blockIdx.x * 256 + threadIdx.x;
    if (r >= 8192) return;
    int j = r & 7, q = (r >> 3) & 3, n = (r >> 5) & 63;
    int k = (r >> 11) * 32 + q * 8 + j;          // 0..127
    if (r < 4096) {                              // k 0..63: layer-1/2 frags
        float ws = w1[k * 64 + n] + w1[4096 + k * 64 + n] + w1[8192 + k * 64 + n];
        wsf[r] = f2bf(ws);
        w2f[r] = f2bf(w2[k * 64 + n]);
    }
    float v = w1[(64 + k) * 64 + n];             // W1b (k<64) / W1c (k>=64)
    unsigned short h = f2bf(v);
    wbh[r] = h;
    wbl[r] = f2bf(v - bf2f(h));
}

// ---------------------------------------------------------------------------
// Fused: block = 16 consecutive CSR groups (~160 rows).
// A1: per-group min/max (fp32, float4 loads, 16 rows in flight) -> LDS.
// A2: bias_g = -(mn@W1b+mx@W1c) via 12 MFMAs (bf16 hi/lo split ~ fp32).
// B : 64-row chunks, both layers via mfma_16x16x32_bf16, stage loads
//     register-prefetched one chunk ahead, 2 barriers per chunk.
// Verified layouts: A[m=lane&15][k=q*8+j], C/D[row=q*4+reg][col=lane&15].
__global__ __launch_bounds__(256, 6)
void fused(const float* __restrict__ x, const int* __restrict__ csr,
           const unsigned short* __restrict__ wsf,
           const unsigned short* __restrict__ w2f,
           const unsigned short* __restrict__ wbh,
           const unsigned short* __restrict__ wbl,
           float* __restrict__ out) {
    __shared__ __align__(16) short xb[64 * 72];   // x chunk, bf16, stride 72
    __shared__ __align__(16) short y1s[64 * 72];  // layer-1 acts; overlaid mnF in phase A
    __shared__ float biasL[GPB * 65];
    __shared__ __align__(16) int rowgrpL[64];
    __shared__ int csrl[GPB + 1];

    const int tid = threadIdx.x, w = tid >> 6, lane = tid & 63;
    const int q = lane >> 4, nl = lane & 15;
    const int jb = w * 16;
    const int n = jb + nl;                        // this lane's output column

    const int g0 = blockIdx.x * GPB;
    const int ng = min(GPB, NGRP - g0);
    if (tid <= ng) csrl[tid] = csr[g0 + tid];
    __syncthreads();
    const int p0 = csrl[0], p1 = csrl[ng];

    // ---- A1: min/max per group (wave-serial over 4 groups), float4 loads.
    // Lanes: sub = lane>>4 picks row offset 0..3, nl picks cols 4*nl..4*nl+3.
    // 4 unrolled loads = 16 rows (4 KB/wave) in flight; clamped row indices
    // produce idempotent duplicates (L1 hits) instead of predication.
    float* mnF = (float*)y1s;                     // [GPB][132] fp32 (8448 B <= 9216)
    {
        const int sub = q;
        const float4* xr = (const float4*)x;
        for (int gl = w; gl < ng; gl += 4) {
            int q0 = csrl[gl], cnt = csrl[gl + 1] - q0;
            if (cnt <= 0) continue;
            float4 mn = { INFINITY, INFINITY, INFINITY, INFINITY };
            float4 mx = { -INFINITY, -INFINITY, -INFINITY, -INFINITY };
            for (int i = 0; i < cnt; i += 16) {
                int ra = q0 + min(i + sub,      cnt - 1);
                int rb = q0 + min(i + sub + 4,  cnt - 1);
                int rc = q0 + min(i + sub + 8,  cnt - 1);
                int rd = q0 + min(i + sub + 12, cnt - 1);
                float4 a = xr[ra * 16 + nl], b = xr[rb * 16 + nl];
                float4 c = xr[rc * 16 + nl], d = xr[rd * 16 + nl];
                mn.x = fminf(mn.x, fminf(fminf(a.x, b.x), fminf(c.x, d.x)));
                mn.y = fminf(mn.y, fminf(fminf(a.y, b.y), fminf(c.y, d.y)));
                mn.z = fminf(mn.z, fminf(fminf(a.z, b.z), fminf(c.z, d.z)));
                mn.w = fminf(mn.w, fminf(fminf(a.w, b.w), fminf(c.w, d.w)));
                mx.x = fmaxf(mx.x, fmaxf(fmaxf(a.x, b.x), fmaxf(c.x, d.x)));
                mx.y = fmaxf(mx.y, fmaxf(fmaxf(a.y, b.y), fmaxf(c.y, d.y)));
                mx.z = fmaxf(mx.z, fmaxf(fmaxf(a.z, b.z), fmaxf(c.z, d.z)));
                mx.w = fmaxf(mx.w, fmaxf(fmaxf(a.w, b.w), fmaxf(c.w, d.w)));
            }
            // combine the 4 row-subsets (lanes xor 16, xor 32)
#pragma unroll
            for (int mk = 16; mk <= 32; mk <<= 1) {
                mn.x = fminf(mn.x, __shfl_xor(mn.x, mk));
                mn.y = fminf(mn.y, __shfl_xor(mn.y, mk));
                mn.z = fminf(mn.z, __shfl_xor(mn.z, mk));
                mn.w = fminf(mn.w, __shfl_xor(mn.w, mk));
                mx.x = fmaxf(mx.x, __shfl_xor(mx.x, mk));
                mx.y = fmaxf(mx.y, __shfl_xor(mx.y, mk));
                mx.z = fmaxf(mx.z, __shfl_xor(mx.z, mk));
                mx.w = fmaxf(mx.w, __shfl_xor(mx.w, mk));
            }
            if (sub == 0) {
                *(float4*)&mnF[gl * 132 + nl * 4]      = mn;   // k 0..63  = mn
                *(float4*)&mnF[gl * 132 + 64 + nl * 4] = mx;   // k 64..127 = mx
            }
        }
    }
    __syncthreads();

    // ---- A2: bias GEMM on MFMA. Output tile: rows = 16 groups, cols = this
    // wave's 16 n's. K=128 ([mn;mx]). hi/lo split: hi@Bh + lo@Bh + hi@Bl.
    // Garbage rows for empty/out-of-range groups are written but never read.
    {
        const bf16x8* bhv = (const bf16x8*)wbh;
        const bf16x8* blv = (const bf16x8*)wbl;
        f32x4 acc = { 0.f, 0.f, 0.f, 0.f };
#pragma unroll
        for (int ks = 0; ks < 4; ++ks) {
            bf16x8 Bh = bhv[(ks * 64 + n) * 4 + q];
            bf16x8 Bl = blv[(ks * 64 + n) * 4 + q];
            const float* ap = &mnF[nl * 132 + ks * 32 + q * 8];  // A[m=nl][k]
            f32x4 v0 = *(const f32x4*)ap;
            f32x4 v1 = *(const f32x4*)(ap + 4);
            bf16x8 ah, al;
#pragma unroll
            for (int jj = 0; jj < 4; ++jj) {
                unsigned short h0 = f2bf(v0[jj]);
                unsigned short h1 = f2bf(v1[jj]);
                ah[jj]     = (short)h0;
                ah[4 + jj] = (short)h1;
                al[jj]     = (short)f2bf(v0[jj] - bf2f(h0));
                al[4 + jj] = (short)f2bf(v1[jj] - bf2f(h1));
            }
            acc = __builtin_amdgcn_mfma_f32_16x16x32_bf16(ah, Bh, acc, 0, 0, 0);
            acc = __builtin_amdgcn_mfma_f32_16x16x32_bf16(al, Bh, acc, 0, 0, 0);
            acc = __builtin_amdgcn_mfma_f32_16x16x32_bf16(ah, Bl, acc, 0, 0, 0);
        }
#pragma unroll
        for (int r = 0; r < 4; ++r)
            biasL[(q * 4 + r) * 65 + n] = -acc[r];   // C/D row = q*4+r = group
    }

    // ---- B-fragments for both layers: held in VGPRs for the whole block
    const bf16x8* wsv = (const bf16x8*)wsf;
    const bf16x8* w2v = (const bf16x8*)w2f;
    bf16x8 B0 = wsv[n * 4 + q];            // layer1, k = q*8..q*8+7
    bf16x8 B1 = wsv[(64 + n) * 4 + q];     // layer1, k = 32+q*8..
    bf16x8 C0 = w2v[n * 4 + q];            // layer2
    bf16x8 C1 = w2v[(64 + n) * 4 + q];

    // prologue: prefetch chunk 0 stage data into registers (overlaps barrier)
    const int nch = (p1 - p0 + 63) >> 6;
    float4 stg[4];
    {
        int availf = min(64, p1 - p0) * 64;
        const float4* x4 = (const float4*)(x + (size_t)p0 * 64);
#pragma unroll
        for (int i = 0; i < 4; ++i) {
            int f = (i * 256 + tid) * 4;
            if (f < availf) stg[i] = x4[f >> 2];
        }
    }
    __syncthreads();   // bias ready; mnF dead -> y1s reusable

    // ---- B: 64-row chunks
    for (int ch = 0; ch < nch; ++ch) {
        const int r0c  = p0 + (ch << 6);
        const int rows = min(64, p1 - r0c);
        const int availf = rows * 64;

        // write staged chunk -> bf16 LDS (values already in registers)
#pragma unroll
        for (int i = 0; i < 4; ++i) {
            int f = (i * 256 + tid) * 4;
            if (f < availf) {
                float4 v = stg[i];
                int r = f >> 6, c = f & 63;
                uint32 lo = (uint32)f2bf(v.x) | ((uint32)f2bf(v.y) << 16);
                uint32 hi = (uint32)f2bf(v.z) | ((uint32)f2bf(v.w) << 16);
                *(uint32*)(&xb[r * 72 + c])     = lo;
                *(uint32*)(&xb[r * 72 + c + 2]) = hi;
            }
        }
        // row -> local group (branch-free binary search), once per chunk
        if (tid < 64) {
            int rs = min(r0c + tid, p1 - 1);
            int lo = 0, hi = ng;
#pragma unroll
            for (int it = 0; it < 5; ++it) {
                int mid = (lo + hi) >> 1;
                bool cb = csrl[mid] <= rs;
                lo = cb ? mid : lo;
                hi = cb ? hi : mid;
            }
            rowgrpL[tid] = lo;
        }
        __syncthreads();   // barrier 1: xb + rowgrpL ready

        // async-stage: issue next chunk's global loads now; their latency
        // hides under layer-1 + barrier 2 + layer-2. Writes happen at the
        // top of the next iteration (after all xb readers passed barrier 2).
        if (ch + 1 < nch) {
            int r0n = r0c + 64;
            int availn = min(64, p1 - r0n) * 64;
            const float4* x4 = (const float4*)(x + (size_t)r0n * 64);
#pragma unroll
            for (int i = 0; i < 4; ++i) {
                int f = (i * 256 + tid) * 4;
                if (f < availn) stg[i] = x4[f >> 2];
            }
        }

        // layer 1: h = leaky(x @ Wsum + bias[g])
        f32x4 h[4];
#pragma unroll
        for (int mt = 0; mt < 4; ++mt) {
            int rbase = mt * 16 + q * 4;
            int4 grp = *(const int4*)(&rowgrpL[rbase]);   // 4 rows' groups, b128
            f32x4 acc;
            acc.x = biasL[grp.x * 65 + n];
            acc.y = biasL[grp.y * 65 + n];
            acc.z = biasL[grp.z * 65 + n];
            acc.w = biasL[grp.w * 65 + n];
            bf16x8 a0 = *(const bf16x8*)(&xb[(mt * 16 + nl) * 72 + q * 8]);
            bf16x8 a1 = *(const bf16x8*)(&xb[(mt * 16 + nl) * 72 + 32 + q * 8]);
            acc = __builtin_amdgcn_mfma_f32_16x16x32_bf16(a0, B0, acc, 0, 0, 0);
            acc = __builtin_amdgcn_mfma_f32_16x16x32_bf16(a1, B1, acc, 0, 0, 0);
            h[mt] = acc;
        }
        // park leaky(h) as bf16 in y1s (C-layout -> A-layout transpose via LDS)
#pragma unroll
        for (int mt = 0; mt < 4; ++mt) {
            int rbase = mt * 16 + q * 4;
#pragma unroll
            for (int r = 0; r < 4; ++r)
                y1s[(rbase + r) * 72 + n] = (short)f2bf(leaky(h[mt][r]));
        }
        __syncthreads();   // barrier 2: y1 ready; xb reads done

        // layer 2: out = leaky(y1 @ W2), direct C-layout NT stores
#pragma unroll
        for (int mt = 0; mt < 4; ++mt) {
            f32x4 acc = {0.f, 0.f, 0.f, 0.f};
            bf16x8 a0 = *(const bf16x8*)(&y1s[(mt * 16 + nl) * 72 + q * 8]);
            bf16x8 a1 = *(const bf16x8*)(&y1s[(mt * 16 + nl) * 72 + 32 + q * 8]);
            acc = __builtin_amdgcn_mfma_f32_16x16x32_bf16(a0, C0, acc, 0, 0, 0);
            acc = __builtin_amdgcn_mfma_f32_16x16x32_bf16(a1, C1, acc, 0, 0, 0);
            int rbase = mt * 16 + q * 4;
#pragma unroll
            for (int r = 0; r < 4; ++r) {
                int rl = rbase + r;
                if (rl < rows)
                    __builtin_nontemporal_store(leaky(acc[r]),
                        &out[(size_t)(r0c + rl) * 64 + n]);
            }
        }
        // no 3rd barrier: laggards in layer 2 touch only y1s/out; leaders
        // write only xb/rowgrpL, whose prior-chunk reads ended before b2.
    }
}

// ---------------------------------------------------------------------------
extern "C" void kernel_launch(void* const* d_in, const int* in_sizes, int n_in,
                              void* d_out, int out_size, void* d_ws, size_t ws_size,
                              hipStream_t stream) {
    const float* x   = (const float*)d_in[0];
    const int*   csr = (const int*)d_in[1];
    const float* w1  = (const float*)d_in[2];
    const float* w2  = (const float*)d_in[3];
    float* out = (float*)d_out;

    unsigned short* wsf = (unsigned short*)d_ws;   // 4096 bf16
    unsigned short* w2f = wsf + 4096;              // 4096 bf16
    unsigned short* wbh = wsf + 8192;              // 8192 bf16 (W1bc hi)
    unsigned short* wbl = wsf + 16384;             // 8192 bf16 (W1bc lo)

    k0_frag<<<32, 256, 0, stream>>>(w1, w2, wsf, w2f, wbh, wbl);
    const int grid = (NGRP + GPB - 1) / GPB;       // 3125
    fused<<<grid, 256, 0, stream>>>(x, csr, wsf, w2f, wbh, wbl, out);
}

// Round 2
// 258.104 us; speedup vs baseline: 1.1453x; 1.0189x over previous
//
#include <hip/hip_runtime.h>
#include <math.h>

#define NROWS 500000
#define NGRP  50000
#define NEG   0.2f
#define GPB   16          // groups per block (50000/16 = 3125 exactly)

typedef __attribute__((ext_vector_type(8))) short bf16x8;   // 8 bf16 = 4 VGPRs
typedef __attribute__((ext_vector_type(4))) float f32x4;    // MFMA C/D
typedef unsigned int uint32;

__device__ __forceinline__ float leaky(float h) { return fmaxf(h, NEG * h); }
__device__ __forceinline__ unsigned short f2bf(float v) {   // RNE (host-side packs only)
    uint32 u = __float_as_uint(v);
    u += 0x7FFFu + ((u >> 16) & 1u);
    return (unsigned short)(u >> 16);
}
__device__ __forceinline__ float bf2f(unsigned short h) {
    return __uint_as_float((uint32)h << 16);
}
// HW packed f32->bf16 (RNE): 1 VALU op for 2 values, result pre-packed.
__device__ __forceinline__ uint32 pkbf(float a, float b) {
    uint32 r;
    asm("v_cvt_pk_bf16_f32 %0, %1, %2" : "=v"(r) : "v"(a), "v"(b));
    return r;
}

// ---------------------------------------------------------------------------
// K0: pack Wsum = W1a+W1b+W1c and W2 into bf16 MFMA B-fragment-major layout:
//   frag[((ks*64 + n)*4 + q)*8 + j] = W[ks*32 + q*8 + j][n]
// Also pack W1bc (w1 rows 64..191, K=128) as a bf16 hi/lo pair for the
// ~fp32-accurate bias MFMA (drop lo*lo).
__global__ void k0_frag(const float* __restrict__ w1, const float* __restrict__ w2,
                        unsigned short* __restrict__ wsf, unsigned short* __restrict__ w2f,
                        unsigned short* __restrict__ wbh, unsigned short* __restrict__ wbl) {
    int r = blockIdx.x * 256 + threadIdx.x;
    if (r >= 8192) return;
    int j = r & 7, q = (r >> 3) & 3, n = (r >> 5) & 63;
    int k = (r >> 11) * 32 + q * 8 + j;          // 0..127
    if (r < 4096) {                              // k 0..63: layer-1/2 frags
        float ws = w1[k * 64 + n] + w1[4096 + k * 64 + n] + w1[8192 + k * 64 + n];
        wsf[r] = f2bf(ws);
        w2f[r] = f2bf(w2[k * 64 + n]);
    }
    float v = w1[(64 + k) * 64 + n];             // W1b (k<64) / W1c (k>=64)
    unsigned short h = f2bf(v);
    wbh[r] = h;
    wbl[r] = f2bf(v - bf2f(h));
}

// ---------------------------------------------------------------------------
// Fused: block = 16 consecutive CSR groups (~160 rows).
// A1: per-group min/max, 2 groups pipelined per wave (8 float4 loads in
//     flight before first reduce) -> LDS fp32.
// A2: bias_g = -(mn@W1b+mx@W1c) via 12 MFMAs (bf16 hi/lo split ~ fp32).
// B : 64-row chunks, both layers via mfma_16x16x32_bf16, stage loads
//     register-prefetched one chunk ahead, 2 barriers per chunk.
// All f32->bf16 conversion via v_cvt_pk_bf16_f32.
// Verified layouts: A[m=lane&15][k=q*8+j], C/D[row=q*4+reg][col=lane&15].
__global__ __launch_bounds__(256, 6)
void fused(const float* __restrict__ x, const int* __restrict__ csr,
           const unsigned short* __restrict__ wsf,
           const unsigned short* __restrict__ w2f,
           const unsigned short* __restrict__ wbh,
           const unsigned short* __restrict__ wbl,
           float* __restrict__ out) {
    __shared__ __align__(16) short xb[64 * 72];   // x chunk, bf16, stride 72
    __shared__ __align__(16) short y1s[64 * 72];  // layer-1 acts; overlaid mnF in phase A
    __shared__ float biasL[GPB * 65];
    __shared__ __align__(16) int rowgrpL[64];
    __shared__ int csrl[GPB + 1];

    const int tid = threadIdx.x, w = tid >> 6, lane = tid & 63;
    const int q = lane >> 4, nl = lane & 15;
    const int jb = w * 16;
    const int n = jb + nl;                        // this lane's output column

    const int g0 = blockIdx.x * GPB;
    const int ng = min(GPB, NGRP - g0);
    if (tid <= ng) csrl[tid] = csr[g0 + tid];
    __syncthreads();
    const int p0 = csrl[0], p1 = csrl[ng];

    // ---- A1: min/max per group. Wave handles 4 groups as 2 pipelined pairs.
    // Lanes: sub = q picks row offset 0..3, nl picks cols 4*nl..4*nl+3.
    // Clamped duplicate rows are idempotent for min/max (L1 hits).
    float* mnF = (float*)y1s;                     // [GPB][132] fp32 (8448 B <= 9216)
    {
        const int sub = q;
        const float4* xr = (const float4*)x;

        auto redgrp = [&](int gl, int q0, int cnt,
                          float4 r0, float4 r1, float4 r2, float4 r3) {
            if (cnt <= 0) return;                 // wave-uniform (gl depends on w only)
            float4 mn, mx;
            mn.x = fminf(fminf(r0.x, r1.x), fminf(r2.x, r3.x));
            mn.y = fminf(fminf(r0.y, r1.y), fminf(r2.y, r3.y));
            mn.z = fminf(fminf(r0.z, r1.z), fminf(r2.z, r3.z));
            mn.w = fminf(fminf(r0.w, r1.w), fminf(r2.w, r3.w));
            mx.x = fmaxf(fmaxf(r0.x, r1.x), fmaxf(r2.x, r3.x));
            mx.y = fmaxf(fmaxf(r0.y, r1.y), fmaxf(r2.y, r3.y));
            mx.z = fmaxf(fmaxf(r0.z, r1.z), fmaxf(r2.z, r3.z));
            mx.w = fmaxf(fmaxf(r0.w, r1.w), fmaxf(r2.w, r3.w));
            for (int i = 16; i < cnt; i += 16) {  // tail (~20% of groups)
                int ra = q0 + min(i + sub,      cnt - 1);
                int rb = q0 + min(i + sub + 4,  cnt - 1);
                int rc = q0 + min(i + sub + 8,  cnt - 1);
                int rd = q0 + min(i + sub + 12, cnt - 1);
                float4 a = xr[ra * 16 + nl], b = xr[rb * 16 + nl];
                float4 c = xr[rc * 16 + nl], d = xr[rd * 16 + nl];
                mn.x = fminf(mn.x, fminf(fminf(a.x, b.x), fminf(c.x, d.x)));
                mn.y = fminf(mn.y, fminf(fminf(a.y, b.y), fminf(c.y, d.y)));
                mn.z = fminf(mn.z, fminf(fminf(a.z, b.z), fminf(c.z, d.z)));
                mn.w = fminf(mn.w, fminf(fminf(a.w, b.w), fminf(c.w, d.w)));
                mx.x = fmaxf(mx.x, fmaxf(fmaxf(a.x, b.x), fmaxf(c.x, d.x)));
                mx.y = fmaxf(mx.y, fmaxf(fmaxf(a.y, b.y), fmaxf(c.y, d.y)));
                mx.z = fmaxf(mx.z, fmaxf(fmaxf(a.z, b.z), fmaxf(c.z, d.z)));
                mx.w = fmaxf(mx.w, fmaxf(fmaxf(a.w, b.w), fmaxf(c.w, d.w)));
            }
#pragma unroll
            for (int mk = 16; mk <= 32; mk <<= 1) {
                mn.x = fminf(mn.x, __shfl_xor(mn.x, mk));
                mn.y = fminf(mn.y, __shfl_xor(mn.y, mk));
                mn.z = fminf(mn.z, __shfl_xor(mn.z, mk));
                mn.w = fminf(mn.w, __shfl_xor(mn.w, mk));
                mx.x = fmaxf(mx.x, __shfl_xor(mx.x, mk));
                mx.y = fmaxf(mx.y, __shfl_xor(mx.y, mk));
                mx.z = fmaxf(mx.z, __shfl_xor(mx.z, mk));
                mx.w = fmaxf(mx.w, __shfl_xor(mx.w, mk));
            }
            if (sub == 0) {
                *(float4*)&mnF[gl * 132 + nl * 4]      = mn;   // k 0..63  = mn
                *(float4*)&mnF[gl * 132 + 64 + nl * 4] = mx;   // k 64..127 = mx
            }
        };

#pragma unroll
        for (int pr = 0; pr < 2; ++pr) {
            const int gA = w + pr * 8, gB = gA + 4;
            int qA = csrl[gA], cA = csrl[gA + 1] - qA;
            int qB = csrl[gB], cB = csrl[gB + 1] - qB;
            const int bA = (cA > 0) ? qA : 0, iA = max(cA - 1, 0);
            const int bB = (cB > 0) ? qB : 0, iB = max(cB - 1, 0);
            // 8 loads (2 groups x 16 rows) in flight before any reduce
            float4 a0 = xr[(bA + min(sub,      iA)) * 16 + nl];
            float4 a1 = xr[(bA + min(sub + 4,  iA)) * 16 + nl];
            float4 a2 = xr[(bA + min(sub + 8,  iA)) * 16 + nl];
            float4 a3 = xr[(bA + min(sub + 12, iA)) * 16 + nl];
            float4 b0 = xr[(bB + min(sub,      iB)) * 16 + nl];
            float4 b1 = xr[(bB + min(sub + 4,  iB)) * 16 + nl];
            float4 b2 = xr[(bB + min(sub + 8,  iB)) * 16 + nl];
            float4 b3 = xr[(bB + min(sub + 12, iB)) * 16 + nl];
            redgrp(gA, qA, cA, a0, a1, a2, a3);
            redgrp(gB, qB, cB, b0, b1, b2, b3);
        }
    }
    __syncthreads();

    // ---- A2: bias GEMM on MFMA. Output tile: rows = 16 groups, cols = this
    // wave's 16 n's. K=128 ([mn;mx]). hi/lo split: hi@Bh + lo@Bh + hi@Bl.
    // Garbage rows for empty groups are written but never read.
    {
        const bf16x8* bhv = (const bf16x8*)wbh;
        const bf16x8* blv = (const bf16x8*)wbl;
        f32x4 acc = { 0.f, 0.f, 0.f, 0.f };
#pragma unroll
        for (int ks = 0; ks < 4; ++ks) {
            bf16x8 Bh = bhv[(ks * 64 + n) * 4 + q];
            bf16x8 Bl = blv[(ks * 64 + n) * 4 + q];
            const float* ap = &mnF[nl * 132 + ks * 32 + q * 8];  // A[m=nl][k]
            f32x4 v0 = *(const f32x4*)ap;
            f32x4 v1 = *(const f32x4*)(ap + 4);
            union U { bf16x8 v; uint32 u[4]; } ah, al;
            ah.u[0] = pkbf(v0[0], v0[1]);
            ah.u[1] = pkbf(v0[2], v0[3]);
            ah.u[2] = pkbf(v1[0], v1[1]);
            ah.u[3] = pkbf(v1[2], v1[3]);
            float r0 = v0[0] - __uint_as_float(ah.u[0] << 16);
            float r1 = v0[1] - __uint_as_float(ah.u[0] & 0xffff0000u);
            float r2 = v0[2] - __uint_as_float(ah.u[1] << 16);
            float r3 = v0[3] - __uint_as_float(ah.u[1] & 0xffff0000u);
            float r4 = v1[0] - __uint_as_float(ah.u[2] << 16);
            float r5 = v1[1] - __uint_as_float(ah.u[2] & 0xffff0000u);
            float r6 = v1[2] - __uint_as_float(ah.u[3] << 16);
            float r7 = v1[3] - __uint_as_float(ah.u[3] & 0xffff0000u);
            al.u[0] = pkbf(r0, r1);
            al.u[1] = pkbf(r2, r3);
            al.u[2] = pkbf(r4, r5);
            al.u[3] = pkbf(r6, r7);
            acc = __builtin_amdgcn_mfma_f32_16x16x32_bf16(ah.v, Bh, acc, 0, 0, 0);
            acc = __builtin_amdgcn_mfma_f32_16x16x32_bf16(al.v, Bh, acc, 0, 0, 0);
            acc = __builtin_amdgcn_mfma_f32_16x16x32_bf16(ah.v, Bl, acc, 0, 0, 0);
        }
#pragma unroll
        for (int r = 0; r < 4; ++r)
            biasL[(q * 4 + r) * 65 + n] = -acc[r];   // C/D row = q*4+r = group
    }

    // ---- B-fragments for both layers: held in VGPRs for the whole block
    const bf16x8* wsv = (const bf16x8*)wsf;
    const bf16x8* w2v = (const bf16x8*)w2f;
    bf16x8 B0 = wsv[n * 4 + q];            // layer1, k = q*8..q*8+7
    bf16x8 B1 = wsv[(64 + n) * 4 + q];     // layer1, k = 32+q*8..
    bf16x8 C0 = w2v[n * 4 + q];            // layer2
    bf16x8 C1 = w2v[(64 + n) * 4 + q];

    // prologue: prefetch chunk 0 stage data into registers (overlaps barrier)
    const int nch = (p1 - p0 + 63) >> 6;
    float4 stg[4];
    {
        int availf = min(64, p1 - p0) * 64;
        const float4* x4 = (const float4*)(x + (size_t)p0 * 64);
#pragma unroll
        for (int i = 0; i < 4; ++i) {
            int f = (i * 256 + tid) * 4;
            if (f < availf) stg[i] = x4[f >> 2];
        }
    }
    __syncthreads();   // bias ready; mnF dead -> y1s reusable

    // ---- B: 64-row chunks
    for (int ch = 0; ch < nch; ++ch) {
        const int r0c  = p0 + (ch << 6);
        const int rows = min(64, p1 - r0c);
        const int availf = rows * 64;

        // write staged chunk -> bf16 LDS (cvt_pk, one ds_write_b64 per float4)
#pragma unroll
        for (int i = 0; i < 4; ++i) {
            int f = (i * 256 + tid) * 4;
            if (f < availf) {
                float4 v = stg[i];
                int r = f >> 6, c = f & 63;
                uint2 p;
                p.x = pkbf(v.x, v.y);
                p.y = pkbf(v.z, v.w);
                *(uint2*)(&xb[r * 72 + c]) = p;
            }
        }
        // row -> local group (branch-free binary search), once per chunk
        if (tid < 64) {
            int rs = min(r0c + tid, p1 - 1);
            int lo = 0, hi = ng;
#pragma unroll
            for (int it = 0; it < 5; ++it) {
                int mid = (lo + hi) >> 1;
                bool cb = csrl[mid] <= rs;
                lo = cb ? mid : lo;
                hi = cb ? hi : mid;
            }
            rowgrpL[tid] = lo;
        }
        __syncthreads();   // barrier 1: xb + rowgrpL ready

        // async-stage: issue next chunk's global loads now; latency hides
        // under layer-1 + barrier 2 + layer-2.
        if (ch + 1 < nch) {
            int r0n = r0c + 64;
            int availn = min(64, p1 - r0n) * 64;
            const float4* x4 = (const float4*)(x + (size_t)r0n * 64);
#pragma unroll
            for (int i = 0; i < 4; ++i) {
                int f = (i * 256 + tid) * 4;
                if (f < availn) stg[i] = x4[f >> 2];
            }
        }

        // layer 1: h = leaky(x @ Wsum + bias[g])
        f32x4 h[4];
#pragma unroll
        for (int mt = 0; mt < 4; ++mt) {
            int rbase = mt * 16 + q * 4;
            int4 grp = *(const int4*)(&rowgrpL[rbase]);   // 4 rows' groups, b128
            f32x4 acc;
            acc.x = biasL[grp.x * 65 + n];
            acc.y = biasL[grp.y * 65 + n];
            acc.z = biasL[grp.z * 65 + n];
            acc.w = biasL[grp.w * 65 + n];
            bf16x8 a0 = *(const bf16x8*)(&xb[(mt * 16 + nl) * 72 + q * 8]);
            bf16x8 a1 = *(const bf16x8*)(&xb[(mt * 16 + nl) * 72 + 32 + q * 8]);
            acc = __builtin_amdgcn_mfma_f32_16x16x32_bf16(a0, B0, acc, 0, 0, 0);
            acc = __builtin_amdgcn_mfma_f32_16x16x32_bf16(a1, B1, acc, 0, 0, 0);
            h[mt] = acc;
        }
        // park leaky(h) as bf16 in y1s (C-layout -> A-layout transpose via LDS)
#pragma unroll
        for (int mt = 0; mt < 4; ++mt) {
            int rbase = mt * 16 + q * 4;
            float h0 = leaky(h[mt][0]);
            float h1 = leaky(h[mt][1]);
            float h2 = leaky(h[mt][2]);
            float h3 = leaky(h[mt][3]);
            uint32 p01 = pkbf(h0, h1);
            uint32 p23 = pkbf(h2, h3);
            y1s[(rbase + 0) * 72 + n] = (short)(p01 & 0xffffu);
            y1s[(rbase + 1) * 72 + n] = (short)(p01 >> 16);
            y1s[(rbase + 2) * 72 + n] = (short)(p23 & 0xffffu);
            y1s[(rbase + 3) * 72 + n] = (short)(p23 >> 16);
        }
        __syncthreads();   // barrier 2: y1 ready; xb reads done

        // layer 2: out = leaky(y1 @ W2), direct C-layout stores (4x64B segs)
#pragma unroll
        for (int mt = 0; mt < 4; ++mt) {
            f32x4 acc = {0.f, 0.f, 0.f, 0.f};
            bf16x8 a0 = *(const bf16x8*)(&y1s[(mt * 16 + nl) * 72 + q * 8]);
            bf16x8 a1 = *(const bf16x8*)(&y1s[(mt * 16 + nl) * 72 + 32 + q * 8]);
            acc = __builtin_amdgcn_mfma_f32_16x16x32_bf16(a0, C0, acc, 0, 0, 0);
            acc = __builtin_amdgcn_mfma_f32_16x16x32_bf16(a1, C1, acc, 0, 0, 0);
            int rbase = mt * 16 + q * 4;
#pragma unroll
            for (int r = 0; r < 4; ++r) {
                int rl = rbase + r;
                if (rl < rows)
                    out[(size_t)(r0c + rl) * 64 + n] = leaky(acc[r]);
            }
        }
        // no 3rd barrier: laggards in layer 2 touch only y1s/out; leaders
        // write only xb/rowgrpL, whose prior-chunk reads ended before b2.
    }
}

// ---------------------------------------------------------------------------
extern "C" void kernel_launch(void* const* d_in, const int* in_sizes, int n_in,
                              void* d_out, int out_size, void* d_ws, size_t ws_size,
                              hipStream_t stream) {
    const float* x   = (const float*)d_in[0];
    const int*   csr = (const int*)d_in[1];
    const float* w1  = (const float*)d_in[2];
    const float* w2  = (const float*)d_in[3];
    float* out = (float*)d_out;

    unsigned short* wsf = (unsigned short*)d_ws;   // 4096 bf16
    unsigned short* w2f = wsf + 4096;              // 4096 bf16
    unsigned short* wbh = wsf + 8192;              // 8192 bf16 (W1bc hi)
    unsigned short* wbl = wsf + 16384;             // 8192 bf16 (W1bc lo)

    k0_frag<<<32, 256, 0, stream>>>(w1, w2, wsf, w2f, wbh, wbl);
    const int grid = (NGRP + GPB - 1) / GPB;       // 3125
    fused<<<grid, 256, 0, stream>>>(x, csr, wsf, w2f, wbh, wbl, out);
}